// Round 8
// baseline (194.549 us; speedup 1.0000x reference)
//
#include <hip/hip_runtime.h>
#include <hip/hip_bf16.h>

// Problem constants: B=2, N=2048, D=512, H=8, hd=64
// (r7 resubmit of the r5-theory kernel: two consecutive infra failures, no kernel evidence;
//  r3 precedent shows infra fails independently of source. Comment tweak to alter source hash.)
typedef __bf16 bf16x8 __attribute__((ext_vector_type(8)));
typedef float f32x4 __attribute__((ext_vector_type(4)));
typedef unsigned short u16x8 __attribute__((ext_vector_type(8)));

#define LOG2E 1.44269504f

__device__ __forceinline__ unsigned short f2bu(float f) {
    __hip_bfloat16 h = __float2bfloat16(f);
    unsigned short u;
    __builtin_memcpy(&u, &h, 2);
    return u;
}

__device__ __forceinline__ float fexp2(float x) {
#if __has_builtin(__builtin_amdgcn_exp2f)
    return __builtin_amdgcn_exp2f(x);
#else
    return __expf(x * 0.69314718f);
#endif
}

__device__ __forceinline__ float bu2f(unsigned short u) {
    unsigned int v = ((unsigned int)u) << 16;
    float f;
    __builtin_memcpy(&f, &v, 4);
    return f;
}

// async global->LDS, 16B per lane. LDS base must be wave-uniform; HW appends lane*16.
#define GLDS16(gp, lp) __builtin_amdgcn_global_load_lds( \
    (const __attribute__((address_space(1))) unsigned int*)(gp), \
    (__attribute__((address_space(3))) unsigned int*)(lp), 16, 0, 0)

// ---- workspace layout (bytes) ----
#define OFF_QS  0u                          // Q*(0.125*log2e) bf16  4 MB
#define OFF_KB  4194304u                    // K bf16                4 MB
#define OFF_VT  8388608u                    // V^T [b,h,d,n] bf16    4 MB
#define OFF_CV  12582912u                   // cv2[b,n] f32 = 2^((c-8)*log2e)  16 KB
#define OFF_XB  12599296u                   // x bf16                4 MB
#define OFF_WT  16793600u                   // W^T bf16              1.5 MB
#define OFF_MQ  18366464u                   // m transposed-perm bf16 16.78 MB
#define OFF_PO  35143680u                   // partial O bf16, 8192 chunks x 1024  16.78 MB
#define OFF_PL  51920896u                   // partial lsum f32, 8192 chunks x 16  512 KB

// ---------------- prep (merged): x->bf16 + cv2, and Wt[n][k] = bf16(W[k][n]) ----------------
__global__ void k_prepwt(const float* __restrict__ x, const float* __restrict__ wg,
                         const float* __restrict__ w0, const float* __restrict__ w1,
                         const float* __restrict__ w2,
                         unsigned short* __restrict__ xb, float* __restrict__ cv2,
                         unsigned short* __restrict__ wt) {
    if (blockIdx.x < 1024) {
        int row = blockIdx.x * 4 + (threadIdx.x >> 6);   // 4096 rows
        int l = threadIdx.x & 63;
        const float4* xr = reinterpret_cast<const float4*>(x + (size_t)row * 512);
        float4 a = xr[l * 2], b2 = xr[l * 2 + 1];
        ushort4 o0, o1;
        o0.x = f2bu(a.x);  o0.y = f2bu(a.y);  o0.z = f2bu(a.z);  o0.w = f2bu(a.w);
        o1.x = f2bu(b2.x); o1.y = f2bu(b2.y); o1.z = f2bu(b2.z); o1.w = f2bu(b2.w);
        ushort4* dst = reinterpret_cast<ushort4*>(xb + (size_t)row * 512);
        dst[l * 2] = o0; dst[l * 2 + 1] = o1;
        const float4* wr = reinterpret_cast<const float4*>(wg + 512);
        float4 g0 = wr[l * 2], g1 = wr[l * 2 + 1];
        float s = a.x * g0.x + a.y * g0.y + a.z * g0.z + a.w * g0.w
                + b2.x * g1.x + b2.y * g1.y + b2.z * g1.z + b2.w * g1.w;
#pragma unroll
        for (int off = 32; off >= 1; off >>= 1) s += __shfl_xor(s, off, 64);
        if (l == 0) cv2[row] = fexp2((s - 8.0f) * LOG2E);
    } else {
        int bid2 = blockIdx.x - 1024;        // 192 blocks: z*64 + yy
        int z = bid2 >> 6, yy = bid2 & 63;
        int k0 = (yy >> 3) * 64, n0 = (yy & 7) * 64;
        const float* W = (z == 0) ? w0 : ((z == 1) ? w1 : w2);
        __shared__ float T[64][65];
        int c = threadIdx.x & 63, r0 = threadIdx.x >> 6;
#pragma unroll
        for (int i = 0; i < 16; i++) { int r = r0 + i * 4; T[r][c] = W[(k0 + r) * 512 + n0 + c]; }
        __syncthreads();
        unsigned short* Wt = wt + z * (512 * 512);
#pragma unroll
        for (int i = 0; i < 16; i++) { int a = r0 + i * 4; Wt[(n0 + a) * 512 + k0 + c] = f2bu(T[c][a]); }
    }
}

// ---------------- merged: QKV GEMM (first, overlaps with adjp) + adjp (transposed perm) ----------------
// gemm (blocks 0..383): 128x128 tile QKV projection, m97-structure (4 waves x 4x4 frags,
//   GLDS16 staging, 2 barriers/K-step); z==2 writes V^T directly.
// adjp (blocks 384..4479): 2 j-tiles per block.
//   mq[((b*128+ic)*32+jt)*1024 + l*16 + mt*4 + r]
//   = bf16((adj[b][ic*16+cl][j] + eps) * cv2[b][j]),  j = jt*64 + 16*mt + q*4 + r, l=q*16+cl.
__global__ __launch_bounds__(256) void k_mid(
    const float* __restrict__ adj, const float* __restrict__ cv2,
    unsigned short* __restrict__ mq,
    const unsigned short* __restrict__ xb, const unsigned short* __restrict__ wt,
    const float* __restrict__ bq, const float* __restrict__ bk, const float* __restrict__ bv,
    unsigned short* __restrict__ Qs, unsigned short* __restrict__ Kb,
    unsigned short* __restrict__ Vt) {
    if (blockIdx.x >= 384) {
        int blk = blockIdx.x - 384;        // bic*16 + jtp
        int bic = blk >> 4, jtp = blk & 15;
        int b = bic >> 7, ic = bic & 127;
        int t = threadIdx.x;               // t = l*4 + mt
        int l = t >> 2, mt = t & 3, q = l >> 4, cl = l & 15;
        const float* arow = adj + ((size_t)(b * 2048 + ic * 16 + cl)) * 2048;
        const float* cvb = cv2 + b * 2048;
#pragma unroll
        for (int e = 0; e < 2; e++) {
            int jt = jtp * 2 + e;
            int j0 = jt * 64 + 16 * mt + q * 4;
            const float4 av = *reinterpret_cast<const float4*>(arow + j0);
            const float4 cv = *reinterpret_cast<const float4*>(cvb + j0);
            ushort4 o;
            o.x = f2bu((av.x + 1e-9f) * cv.x);
            o.y = f2bu((av.y + 1e-9f) * cv.y);
            o.z = f2bu((av.z + 1e-9f) * cv.z);
            o.w = f2bu((av.w + 1e-9f) * cv.w);
            *reinterpret_cast<ushort4*>(mq + (size_t)bic * 32768 + jt * 1024 + l * 16 + mt * 4) = o;
        }
        return;
    }
    int gid = blockIdx.x;                  // 384: bx(32) by(4) z(3)
    int bx = gid & 31, by = (gid >> 5) & 3, z = gid >> 7;
    __shared__ __align__(16) unsigned short As[128 * 32];
    __shared__ __align__(16) unsigned short Bs[128 * 32];
    const unsigned short* Wt = wt + z * (512 * 512);
    const float* bias = (z == 0) ? bq : ((z == 1) ? bk : bv);
    float scale = (z == 0) ? (0.125f * LOG2E) : 1.0f;   // Q pre-scaled by log2e/sqrt(64)
    int m0 = bx * 128, n0 = by * 128;
    int tid = threadIdx.x, w = tid >> 6, l = tid & 63;
    int q = l >> 4, cl = l & 15;
    int wr = w >> 1, wc = w & 1;           // wave quadrant: rows wr*64, cols wc*64
    f32x4 acc[4][4];
#pragma unroll
    for (int mi = 0; mi < 4; mi++)
#pragma unroll
        for (int ni = 0; ni < 4; ni++)
#pragma unroll
            for (int r = 0; r < 4; r++) acc[mi][ni][r] = 0.f;
    int arow = l >> 2, ach = (l & 3) * 8;
    for (int k0 = 0; k0 < 512; k0 += 32) {
#pragma unroll
        for (int e = 0; e < 2; e++) {
            GLDS16(xb + (size_t)(m0 + w * 32 + e * 16 + arow) * 512 + k0 + ach, As + (w * 32 + e * 16) * 32);
            GLDS16(Wt + (size_t)(n0 + w * 32 + e * 16 + arow) * 512 + k0 + ach, Bs + (w * 32 + e * 16) * 32);
        }
        __syncthreads();
        bf16x8 af[4], bfr[4];
#pragma unroll
        for (int i = 0; i < 4; i++) {
            af[i]  = *reinterpret_cast<const bf16x8*>(As + (wr * 64 + i * 16 + cl) * 32 + q * 8);
            bfr[i] = *reinterpret_cast<const bf16x8*>(Bs + (wc * 64 + i * 16 + cl) * 32 + q * 8);
        }
#pragma unroll
        for (int mi = 0; mi < 4; mi++)
#pragma unroll
            for (int ni = 0; ni < 4; ni++)
                acc[mi][ni] = __builtin_amdgcn_mfma_f32_16x16x32_bf16(af[mi], bfr[ni], acc[mi][ni], 0, 0, 0);
        __syncthreads();
    }
    if (z == 2) {
        int b_ = (m0 + wr * 64) >> 11;     // 128-tiles never straddle batch boundary
#pragma unroll
        for (int mi = 0; mi < 4; mi++) {
            int n_ = (m0 + wr * 64 + mi * 16 + q * 4) & 2047;
#pragma unroll
            for (int ni = 0; ni < 4; ni++) {
                int col = n0 + wc * 64 + ni * 16 + cl;
                int h_ = col >> 6, d_ = col & 63;
                float bv_ = bias[col];
                ushort4 o;
                o.x = f2bu(acc[mi][ni][0] + bv_); o.y = f2bu(acc[mi][ni][1] + bv_);
                o.z = f2bu(acc[mi][ni][2] + bv_); o.w = f2bu(acc[mi][ni][3] + bv_);
                *reinterpret_cast<ushort4*>(Vt + ((size_t)((b_ * 8 + h_) * 64 + d_)) * 2048 + n_) = o;
            }
        }
    } else {
        unsigned short* Cout = (z == 0) ? Qs : Kb;
#pragma unroll
        for (int mi = 0; mi < 4; mi++)
#pragma unroll
            for (int ni = 0; ni < 4; ni++) {
                int col = n0 + wc * 64 + ni * 16 + cl;
                float bv_ = bias[col];
#pragma unroll
                for (int r = 0; r < 4; r++) {
                    int row = m0 + wr * 64 + mi * 16 + q * 4 + r;
                    Cout[(size_t)row * 512 + col] = f2bu((acc[mi][ni][r] + bv_) * scale);
                }
            }
    }
}

// ---------------- flash attention: transposed-S, K dbuf LDS, V direct global (pinned issue) ----------------
// 1024 blocks x 256 thr, 3 blocks/CU (12 waves/CU). bid = h*128 + b*64 + ig*4 + js.
// Wave w: rows [ig*128 + w*32, +32) as 2 chunks rc; j-range [js*512,+512) = 8 tiles of 64.
// r5 counters proved r4 is LDS-throughput-bound (~28 KB/wave/tile = ~2600cy/CU/tile-round =
// measured Ttile). V B-fragments are a direct contiguous 16B slice of Vt -> load global->VGPR
// at tile top; __builtin_amdgcn_sched_barrier(0) right after PINS the issue point (r5's failure:
// compiler sank these loads to PV, VGPR 84, latency-bound 68µs). waitcnt still lands at PV use.
// Osum MFMAs replaced by per-lane f32 row-sum adds (frees ones+Osum regs to fit vfr under the
// 170-VGPR cliff of launch_bounds(256,3)). mcA/mcB ping-pong kept exactly as r4 (proven).
// LDS 50->34.4 KB; traffic 28->18 KB/wave/tile.
__global__ __launch_bounds__(256, 3) void k_attn(
    const unsigned short* __restrict__ Qs, const unsigned short* __restrict__ Kb,
    const unsigned short* __restrict__ Vt, const unsigned short* __restrict__ mq,
    unsigned short* __restrict__ PO, float* __restrict__ PL) {
    __shared__ __align__(16) unsigned short Ks[2][4096];   // [buf][kk][64 j][32 d]
    __shared__ __align__(16) unsigned short PA[4][32 * 72];  // per-wave P[i][j] (2 rc), stride 72
    int bid = blockIdx.x;
    int h = bid >> 7, b = (bid >> 6) & 1, ig = (bid >> 2) & 15, js = bid & 3;
    int tid = threadIdx.x, w = tid >> 6, l = tid & 63, q = l >> 4, cl = l & 15;
    int bh = b * 8 + h;
    int ic0 = ig * 8 + w * 2;

    // Q^T B-fragments for 2 row-chunks, loop-invariant
    bf16x8 qf[2][2];
#pragma unroll
    for (int rc = 0; rc < 2; rc++) {
        const unsigned short* qp = Qs + (size_t)(b * 2048 + ig * 128 + w * 32 + rc * 16 + cl) * 512 + h * 64 + q * 8;
        qf[rc][0] = *reinterpret_cast<const bf16x8*>(qp);
        qf[rc][1] = *reinterpret_cast<const bf16x8*>(qp + 32);
    }

    f32x4 O[2][4];
#pragma unroll
    for (int rc = 0; rc < 2; rc++)
#pragma unroll
        for (int nt = 0; nt < 4; nt++)
#pragma unroll
            for (int r = 0; r < 4; r++) O[rc][nt][r] = 0.f;
    float ls[2] = {0.f, 0.f};   // per-lane partial row-sum for row i=cl (reduced across q at end)

    const unsigned short* Kh = Kb + (size_t)b * 2048 * 512 + h * 64;
    const unsigned short* Vh = Vt + ((size_t)bh * 64) * 2048;
    const unsigned short* mb0 = mq + (size_t)(b * 128 + ic0) * 32768 + l * 16 + (size_t)(js * 8) * 1024;
    const unsigned short* mb1 = mb0 + 32768;
    unsigned short* pw = &PA[w][0];
    int lrow = l >> 2, lch = (l & 3) * 8;
    int jb0 = js * 512;
    // per-lane V base: row d = 16*nt + cl, j-offset T*64 + jc*32 + q*8
    const unsigned short* Vl = Vh + (size_t)cl * 2048 + jb0 + q * 8;

    // stage K tile 0 into buf 0
#pragma unroll
    for (int e = 0; e < 2; e++) {
        int c = w * 2 + e, kk = c >> 2, r16 = (c & 3) * 16;
        GLDS16(Kh + (size_t)(jb0 + r16 + lrow) * 512 + kk * 32 + lch, &Ks[0][kk * 2048 + r16 * 32]);
    }
    // prefetch mc for tile 0
    u16x8 mcA[2][2], mcB[2][2];
    mcA[0][0] = *reinterpret_cast<const u16x8*>(mb0);
    mcA[0][1] = *reinterpret_cast<const u16x8*>(mb0 + 8);
    mcA[1][0] = *reinterpret_cast<const u16x8*>(mb1);
    mcA[1][1] = *reinterpret_cast<const u16x8*>(mb1 + 8);

// One tile body. BUF is a literal (static LDS addressing); MCC = mc regs for this tile
// (prefetched last iteration); MCN = regs to prefetch tile T+1 into; PRED = stage-next?
#define ATT_BODY(T, BUF, MCC, MCN, PRED) { \
    __syncthreads();   /* K tile T staged (vmcnt drained pre-barrier; issued a full iter ago) */ \
    /* V fragments for tile T: direct global (L2). Issue pinned HERE; waitcnt lands at PV. */ \
    bf16x8 vfr[2][4]; \
    _Pragma("unroll") \
    for (int jc = 0; jc < 2; jc++) \
        _Pragma("unroll") \
        for (int nt = 0; nt < 4; nt++) \
            vfr[jc][nt] = *reinterpret_cast<const bf16x8*>(Vl + (size_t)(nt * 16) * 2048 + (T) * 64 + jc * 32); \
    __builtin_amdgcn_sched_barrier(0); \
    if (PRED) { \
        int jb = jb0 + ((T) + 1) * 64; \
        _Pragma("unroll") \
        for (int e = 0; e < 2; e++) { \
            int c = w * 2 + e, kk = c >> 2, r16 = (c & 3) * 16; \
            GLDS16(Kh + (size_t)(jb + r16 + lrow) * 512 + kk * 32 + lch, &Ks[(BUF) ^ 1][kk * 2048 + r16 * 32]); \
        } \
        size_t off = (size_t)((T) + 1) * 1024; \
        MCN[0][0] = *reinterpret_cast<const u16x8*>(mb0 + off); \
        MCN[0][1] = *reinterpret_cast<const u16x8*>(mb0 + off + 8); \
        MCN[1][0] = *reinterpret_cast<const u16x8*>(mb1 + off); \
        MCN[1][1] = *reinterpret_cast<const u16x8*>(mb1 + off + 8); \
    } \
    /* S^T = K.Q^T for both rc (K fragments read once) */ \
    f32x4 S[2][4]; \
    _Pragma("unroll") \
    for (int rc = 0; rc < 2; rc++) \
        _Pragma("unroll") \
        for (int mt = 0; mt < 4; mt++) \
            _Pragma("unroll") \
            for (int r = 0; r < 4; r++) S[rc][mt][r] = 0.f; \
    __builtin_amdgcn_s_setprio(1); \
    _Pragma("unroll") \
    for (int mt = 0; mt < 4; mt++) { \
        bf16x8 kf0 = *reinterpret_cast<const bf16x8*>(&Ks[BUF][(16 * mt + cl) * 32 + q * 8]); \
        bf16x8 kf1 = *reinterpret_cast<const bf16x8*>(&Ks[BUF][2048 + (16 * mt + cl) * 32 + q * 8]); \
        _Pragma("unroll") \
        for (int rc = 0; rc < 2; rc++) { \
            S[rc][mt] = __builtin_amdgcn_mfma_f32_16x16x32_bf16(kf0, qf[rc][0], S[rc][mt], 0, 0, 0); \
            S[rc][mt] = __builtin_amdgcn_mfma_f32_16x16x32_bf16(kf1, qf[rc][1], S[rc][mt], 0, 0, 0); \
        } \
    } \
    __builtin_amdgcn_s_setprio(0); \
    /* per rc: p = exp2(S^T)*m -> PA (b64 writes); accumulate per-lane row-sum in f32 */ \
    _Pragma("unroll") \
    for (int rc = 0; rc < 2; rc++) { \
        _Pragma("unroll") \
        for (int mt = 0; mt < 4; mt++) { \
            float p0 = fexp2(S[rc][mt][0]) * bu2f((mt < 2) ? MCC[rc][0][mt * 4 + 0] : MCC[rc][1][(mt - 2) * 4 + 0]); \
            float p1 = fexp2(S[rc][mt][1]) * bu2f((mt < 2) ? MCC[rc][0][mt * 4 + 1] : MCC[rc][1][(mt - 2) * 4 + 1]); \
            float p2 = fexp2(S[rc][mt][2]) * bu2f((mt < 2) ? MCC[rc][0][mt * 4 + 2] : MCC[rc][1][(mt - 2) * 4 + 2]); \
            float p3 = fexp2(S[rc][mt][3]) * bu2f((mt < 2) ? MCC[rc][0][mt * 4 + 3] : MCC[rc][1][(mt - 2) * 4 + 3]); \
            ushort4 o; \
            o.x = f2bu(p0); o.y = f2bu(p1); o.z = f2bu(p2); o.w = f2bu(p3); \
            ls[rc] += (bu2f(o.x) + bu2f(o.y)) + (bu2f(o.z) + bu2f(o.w)); \
            *reinterpret_cast<ushort4*>(pw + rc * (16 * 72) + cl * 72 + 16 * mt + q * 4) = o; \
        } \
    } \
    /* O += P.V: per jc read both rc P-fragments, V fragments from regs (loaded at tile top) */ \
    __builtin_amdgcn_s_setprio(1); \
    _Pragma("unroll") \
    for (int jc = 0; jc < 2; jc++) { \
        bf16x8 pf0 = *reinterpret_cast<const bf16x8*>(pw + cl * 72 + jc * 32 + q * 8); \
        bf16x8 pf1 = *reinterpret_cast<const bf16x8*>(pw + 16 * 72 + cl * 72 + jc * 32 + q * 8); \
        _Pragma("unroll") \
        for (int nt = 0; nt < 4; nt++) { \
            O[0][nt] = __builtin_amdgcn_mfma_f32_16x16x32_bf16(pf0, vfr[jc][nt], O[0][nt], 0, 0, 0); \
            O[1][nt] = __builtin_amdgcn_mfma_f32_16x16x32_bf16(pf1, vfr[jc][nt], O[1][nt], 0, 0, 0); \
        } \
    } \
    __builtin_amdgcn_s_setprio(0); \
}

    for (int tt = 0; tt < 4; tt++) {
        int t0 = tt * 2;
        ATT_BODY(t0, 0, mcA, mcB, 1)
        ATT_BODY(t0 + 1, 1, mcB, mcA, (tt < 3))
    }
#undef ATT_BODY

    // epilogue: write bf16 partial O (lane-packed, 16B stores) + row sums
    // row-sum: lane (q,cl) holds partial for row i=cl; reduce across the 4 q-lanes.
    typedef unsigned short u16x8s __attribute__((ext_vector_type(8)));
#pragma unroll
    for (int rc = 0; rc < 2; rc++) {
        size_t chunk = ((size_t)(bh * 128 + ic0 + rc)) * 4 + js;
        unsigned short* po = PO + chunk * 1024 + l * 16;
        u16x8s o01, o23;
#pragma unroll
        for (int nt = 0; nt < 4; nt++) {
            o01[nt]     = f2bu(O[rc][nt][0]);
            o01[4 + nt] = f2bu(O[rc][nt][1]);
            o23[nt]     = f2bu(O[rc][nt][2]);
            o23[4 + nt] = f2bu(O[rc][nt][3]);
        }
        *reinterpret_cast<u16x8s*>(po) = o01;
        *reinterpret_cast<u16x8s*>(po + 8) = o23;
        float lsum = ls[rc];
        lsum += __shfl_xor(lsum, 16, 64);
        lsum += __shfl_xor(lsum, 32, 64);
        if (q == 0) PL[chunk * 16 + cl] = lsum;
    }
}

// ---------------- combine 4 j-quarters, normalize, residual ----------------
// 512 blocks (bh*32 + t64) x 256 thr; each block 4 row-chunks (64 rows).
__global__ void k_comb(const unsigned short* __restrict__ PO, const float* __restrict__ PL,
                       const float* __restrict__ x, float* __restrict__ out) {
    int blk = blockIdx.x;
    int t64 = blk & 31, bh = blk >> 5;
    int b = bh >> 3, h = bh & 7;
    int t = threadIdx.x;               // t = l*4 + r
    int l = t >> 2, r = t & 3, q = l >> 4, cl = l & 15;
#pragma unroll
    for (int w = 0; w < 4; w++) {
        int ic = t64 * 4 + w;
        size_t c0 = ((size_t)(bh * 128 + ic)) * 4;
        float o0 = 0.f, o1 = 0.f, o2 = 0.f, o3 = 0.f, lsum = 0.f;
#pragma unroll
        for (int js = 0; js < 4; js++) {
            ushort4 a = *reinterpret_cast<const ushort4*>(PO + (c0 + js) * 1024 + t * 4);
            o0 += bu2f(a.x); o1 += bu2f(a.y); o2 += bu2f(a.z); o3 += bu2f(a.w);
            lsum += PL[(c0 + js) * 16 + q * 4 + r];
        }
        float inv = 1.0f / lsum;
        size_t gro = (size_t)(b * 2048 + ic * 16 + q * 4 + r) * 512 + h * 64;
        out[gro + 0 * 16 + cl] = o0 * inv + x[gro + 0 * 16 + cl];
        out[gro + 1 * 16 + cl] = o1 * inv + x[gro + 1 * 16 + cl];
        out[gro + 2 * 16 + cl] = o2 * inv + x[gro + 2 * 16 + cl];
        out[gro + 3 * 16 + cl] = o3 * inv + x[gro + 3 * 16 + cl];
    }
}

extern "C" void kernel_launch(void* const* d_in, const int* in_sizes, int n_in,
                              void* d_out, int out_size, void* d_ws, size_t ws_size,
                              hipStream_t stream) {
    const float* x   = (const float*)d_in[0];
    const float* adj = (const float*)d_in[1];
    const float* Wq  = (const float*)d_in[2];
    const float* bq  = (const float*)d_in[3];
    const float* Wk  = (const float*)d_in[4];
    const float* bk  = (const float*)d_in[5];
    const float* Wv  = (const float*)d_in[6];
    const float* bv  = (const float*)d_in[7];
    const float* wg  = (const float*)d_in[8];
    // d_in[9] (b_g) unused: row-constant bias cancels in softmax
    float* out = (float*)d_out;
    char* ws = (char*)d_ws;
    unsigned short* Qs = (unsigned short*)(ws + OFF_QS);
    unsigned short* Kb = (unsigned short*)(ws + OFF_KB);
    unsigned short* Vt = (unsigned short*)(ws + OFF_VT);
    float* cv2 = (float*)(ws + OFF_CV);
    unsigned short* xb = (unsigned short*)(ws + OFF_XB);
    unsigned short* wt = (unsigned short*)(ws + OFF_WT);
    unsigned short* mqp = (unsigned short*)(ws + OFF_MQ);
    unsigned short* PO = (unsigned short*)(ws + OFF_PO);
    float* PL = (float*)(ws + OFF_PL);

    k_prepwt<<<1216, 256, 0, stream>>>(x, wg, Wq, Wk, Wv, xb, cv2, wt);
    k_mid<<<4480, 256, 0, stream>>>(adj, cv2, mqp, xb, wt, bq, bk, bv, Qs, Kb, Vt);
    k_attn<<<1024, 256, 0, stream>>>(Qs, Kb, Vt, mqp, PO, PL);
    k_comb<<<512, 256, 0, stream>>>(PO, PL, x, out);
}

// Round 9
// 149.265 us; speedup vs baseline: 1.3034x; 1.3034x over previous
//
#include <hip/hip_runtime.h>
#include <hip/hip_bf16.h>

// Problem constants: B=2, N=2048, D=512, H=8, hd=64
typedef __bf16 bf16x8 __attribute__((ext_vector_type(8)));
typedef float f32x4 __attribute__((ext_vector_type(4)));
typedef unsigned short u16x8 __attribute__((ext_vector_type(8)));

#define LOG2E 1.44269504f

__device__ __forceinline__ unsigned short f2bu(float f) {
    __hip_bfloat16 h = __float2bfloat16(f);
    unsigned short u;
    __builtin_memcpy(&u, &h, 2);
    return u;
}

__device__ __forceinline__ float fexp2(float x) {
#if __has_builtin(__builtin_amdgcn_exp2f)
    return __builtin_amdgcn_exp2f(x);
#else
    return __expf(x * 0.69314718f);
#endif
}

__device__ __forceinline__ float bu2f(unsigned short u) {
    unsigned int v = ((unsigned int)u) << 16;
    float f;
    __builtin_memcpy(&f, &v, 4);
    return f;
}

// async global->LDS, 16B per lane. LDS base must be wave-uniform; HW appends lane*16.
#define GLDS16(gp, lp) __builtin_amdgcn_global_load_lds( \
    (const __attribute__((address_space(1))) unsigned int*)(gp), \
    (__attribute__((address_space(3))) unsigned int*)(lp), 16, 0, 0)

// ---- workspace layout (bytes) ----
#define OFF_QS  0u                          // Q*(0.125*log2e) bf16  4 MB
#define OFF_KB  4194304u                    // K bf16                4 MB
#define OFF_VT  8388608u                    // V^T [b,h,d,n] bf16    4 MB
#define OFF_CV  12582912u                   // cv2[b,n] f32 = 2^((c-8)*log2e)  16 KB
#define OFF_XB  12599296u                   // x bf16                4 MB
#define OFF_WT  16793600u                   // W^T bf16              1.5 MB
#define OFF_MQ  18366464u                   // m transposed-perm bf16 16.78 MB
#define OFF_PO  35143680u                   // partial O bf16, 4096 chunks x 1024  8.39 MB
#define OFF_PL  51920896u                   // partial lsum f32, 4096 chunks x 16  256 KB

// ---------------- prep (merged): x->bf16 + cv2, and Wt[n][k] = bf16(W[k][n]) ----------------
__global__ void k_prepwt(const float* __restrict__ x, const float* __restrict__ wg,
                         const float* __restrict__ w0, const float* __restrict__ w1,
                         const float* __restrict__ w2,
                         unsigned short* __restrict__ xb, float* __restrict__ cv2,
                         unsigned short* __restrict__ wt) {
    if (blockIdx.x < 1024) {
        int row = blockIdx.x * 4 + (threadIdx.x >> 6);   // 4096 rows
        int l = threadIdx.x & 63;
        const float4* xr = reinterpret_cast<const float4*>(x + (size_t)row * 512);
        float4 a = xr[l * 2], b2 = xr[l * 2 + 1];
        ushort4 o0, o1;
        o0.x = f2bu(a.x);  o0.y = f2bu(a.y);  o0.z = f2bu(a.z);  o0.w = f2bu(a.w);
        o1.x = f2bu(b2.x); o1.y = f2bu(b2.y); o1.z = f2bu(b2.z); o1.w = f2bu(b2.w);
        ushort4* dst = reinterpret_cast<ushort4*>(xb + (size_t)row * 512);
        dst[l * 2] = o0; dst[l * 2 + 1] = o1;
        const float4* wr = reinterpret_cast<const float4*>(wg + 512);
        float4 g0 = wr[l * 2], g1 = wr[l * 2 + 1];
        float s = a.x * g0.x + a.y * g0.y + a.z * g0.z + a.w * g0.w
                + b2.x * g1.x + b2.y * g1.y + b2.z * g1.z + b2.w * g1.w;
#pragma unroll
        for (int off = 32; off >= 1; off >>= 1) s += __shfl_xor(s, off, 64);
        if (l == 0) cv2[row] = fexp2((s - 8.0f) * LOG2E);
    } else {
        int bid2 = blockIdx.x - 1024;        // 192 blocks: z*64 + yy
        int z = bid2 >> 6, yy = bid2 & 63;
        int k0 = (yy >> 3) * 64, n0 = (yy & 7) * 64;
        const float* W = (z == 0) ? w0 : ((z == 1) ? w1 : w2);
        __shared__ float T[64][65];
        int c = threadIdx.x & 63, r0 = threadIdx.x >> 6;
#pragma unroll
        for (int i = 0; i < 16; i++) { int r = r0 + i * 4; T[r][c] = W[(k0 + r) * 512 + n0 + c]; }
        __syncthreads();
        unsigned short* Wt = wt + z * (512 * 512);
#pragma unroll
        for (int i = 0; i < 16; i++) { int a = r0 + i * 4; Wt[(n0 + a) * 512 + k0 + c] = f2bu(T[c][a]); }
    }
}

// ---------------- merged: QKV GEMM (first, overlaps with adjp) + adjp (transposed perm) ----------------
// gemm (blocks 0..383): 128x128 tile QKV projection, m97-structure (4 waves x 4x4 frags,
//   GLDS16 staging, 2 barriers/K-step); z==2 writes V^T directly.
// adjp (blocks 384..4479): 2 j-tiles per block.
//   mq[((b*128+ic)*32+jt)*1024 + l*16 + mt*4 + r]
//   = bf16((adj[b][ic*16+cl][j] + eps) * cv2[b][j]),  j = jt*64 + 16*mt + q*4 + r, l=q*16+cl.
__global__ __launch_bounds__(256) void k_mid(
    const float* __restrict__ adj, const float* __restrict__ cv2,
    unsigned short* __restrict__ mq,
    const unsigned short* __restrict__ xb, const unsigned short* __restrict__ wt,
    const float* __restrict__ bq, const float* __restrict__ bk, const float* __restrict__ bv,
    unsigned short* __restrict__ Qs, unsigned short* __restrict__ Kb,
    unsigned short* __restrict__ Vt) {
    if (blockIdx.x >= 384) {
        int blk = blockIdx.x - 384;        // bic*16 + jtp
        int bic = blk >> 4, jtp = blk & 15;
        int b = bic >> 7, ic = bic & 127;
        int t = threadIdx.x;               // t = l*4 + mt
        int l = t >> 2, mt = t & 3, q = l >> 4, cl = l & 15;
        const float* arow = adj + ((size_t)(b * 2048 + ic * 16 + cl)) * 2048;
        const float* cvb = cv2 + b * 2048;
#pragma unroll
        for (int e = 0; e < 2; e++) {
            int jt = jtp * 2 + e;
            int j0 = jt * 64 + 16 * mt + q * 4;
            const float4 av = *reinterpret_cast<const float4*>(arow + j0);
            const float4 cv = *reinterpret_cast<const float4*>(cvb + j0);
            ushort4 o;
            o.x = f2bu((av.x + 1e-9f) * cv.x);
            o.y = f2bu((av.y + 1e-9f) * cv.y);
            o.z = f2bu((av.z + 1e-9f) * cv.z);
            o.w = f2bu((av.w + 1e-9f) * cv.w);
            *reinterpret_cast<ushort4*>(mq + (size_t)bic * 32768 + jt * 1024 + l * 16 + mt * 4) = o;
        }
        return;
    }
    int gid = blockIdx.x;                  // 384: bx(32) by(4) z(3)
    int bx = gid & 31, by = (gid >> 5) & 3, z = gid >> 7;
    __shared__ __align__(16) unsigned short As[128 * 32];
    __shared__ __align__(16) unsigned short Bs[128 * 32];
    const unsigned short* Wt = wt + z * (512 * 512);
    const float* bias = (z == 0) ? bq : ((z == 1) ? bk : bv);
    float scale = (z == 0) ? (0.125f * LOG2E) : 1.0f;   // Q pre-scaled by log2e/sqrt(64)
    int m0 = bx * 128, n0 = by * 128;
    int tid = threadIdx.x, w = tid >> 6, l = tid & 63;
    int q = l >> 4, cl = l & 15;
    int wr = w >> 1, wc = w & 1;           // wave quadrant: rows wr*64, cols wc*64
    f32x4 acc[4][4];
#pragma unroll
    for (int mi = 0; mi < 4; mi++)
#pragma unroll
        for (int ni = 0; ni < 4; ni++)
#pragma unroll
            for (int r = 0; r < 4; r++) acc[mi][ni][r] = 0.f;
    int arow = l >> 2, ach = (l & 3) * 8;
    for (int k0 = 0; k0 < 512; k0 += 32) {
#pragma unroll
        for (int e = 0; e < 2; e++) {
            GLDS16(xb + (size_t)(m0 + w * 32 + e * 16 + arow) * 512 + k0 + ach, As + (w * 32 + e * 16) * 32);
            GLDS16(Wt + (size_t)(n0 + w * 32 + e * 16 + arow) * 512 + k0 + ach, Bs + (w * 32 + e * 16) * 32);
        }
        __syncthreads();
        bf16x8 af[4], bfr[4];
#pragma unroll
        for (int i = 0; i < 4; i++) {
            af[i]  = *reinterpret_cast<const bf16x8*>(As + (wr * 64 + i * 16 + cl) * 32 + q * 8);
            bfr[i] = *reinterpret_cast<const bf16x8*>(Bs + (wc * 64 + i * 16 + cl) * 32 + q * 8);
        }
#pragma unroll
        for (int mi = 0; mi < 4; mi++)
#pragma unroll
            for (int ni = 0; ni < 4; ni++)
                acc[mi][ni] = __builtin_amdgcn_mfma_f32_16x16x32_bf16(af[mi], bfr[ni], acc[mi][ni], 0, 0, 0);
        __syncthreads();
    }
    if (z == 2) {
        int b_ = (m0 + wr * 64) >> 11;     // 128-tiles never straddle batch boundary
#pragma unroll
        for (int mi = 0; mi < 4; mi++) {
            int n_ = (m0 + wr * 64 + mi * 16 + q * 4) & 2047;
#pragma unroll
            for (int ni = 0; ni < 4; ni++) {
                int col = n0 + wc * 64 + ni * 16 + cl;
                int h_ = col >> 6, d_ = col & 63;
                float bv_ = bias[col];
                ushort4 o;
                o.x = f2bu(acc[mi][ni][0] + bv_); o.y = f2bu(acc[mi][ni][1] + bv_);
                o.z = f2bu(acc[mi][ni][2] + bv_); o.w = f2bu(acc[mi][ni][3] + bv_);
                *reinterpret_cast<ushort4*>(Vt + ((size_t)((b_ * 8 + h_) * 64 + d_)) * 2048 + n_) = o;
            }
        }
    } else {
        unsigned short* Cout = (z == 0) ? Qs : Kb;
#pragma unroll
        for (int mi = 0; mi < 4; mi++)
#pragma unroll
            for (int ni = 0; ni < 4; ni++) {
                int col = n0 + wc * 64 + ni * 16 + cl;
                float bv_ = bias[col];
#pragma unroll
                for (int r = 0; r < 4; r++) {
                    int row = m0 + wr * 64 + mi * 16 + q * 4 + r;
                    Cout[(size_t)row * 512 + col] = f2bu((acc[mi][ni][r] + bv_) * scale);
                }
            }
    }
}

// ---------------- flash attention: transposed-S, dbuf LDS, 32 rows/wave, j-HALVES ----------------
// 512 blocks x 256 thr (2 blocks/CU exactly, uniform residency). bid = h*64 + b*32 + ig*2 + js.
// Wave w: rows [ig*128 + w*32, +32) as 2 chunks rc; j-range [js*1024,+1024) = 16 tiles of 64.
// Body is the r4-VERIFIED structure (V staged in LDS, mcA/mcB ping-pong, rolled tt-loop).
// j-split 4->2 halves the PO/PL round-trip and evens block residency; per-block O accumulates
// 1024 j in f32 before one bf16 rounding (precision >=).
// r2/r5/r8 post-mortem: V-direct-from-L2 is structurally infeasible at (256,3) — unified
// VGPR/AGPR budget ~170 leaves ~84 arch-VGPRs; vfr's +32 live-across-softmax always spills
// or sinks. DO NOT retry V-in-regs at this occupancy.
__global__ __launch_bounds__(256, 3) void k_attn(
    const unsigned short* __restrict__ Qs, const unsigned short* __restrict__ Kb,
    const unsigned short* __restrict__ Vt, const unsigned short* __restrict__ mq,
    unsigned short* __restrict__ PO, float* __restrict__ PL) {
    __shared__ __align__(16) unsigned short Ks[2][4096];   // [buf][kk][64 j][32 d]
    __shared__ __align__(16) unsigned short Vs[2][4096];   // [buf][jc][64 d][32 j]
    __shared__ __align__(16) unsigned short PA[4][32 * 72];  // per-wave P[i][j] (2 rc), stride 72
    int bid = blockIdx.x;
    int h = bid >> 6, b = (bid >> 5) & 1, ig = (bid >> 1) & 15, js = bid & 1;
    int tid = threadIdx.x, w = tid >> 6, l = tid & 63, q = l >> 4, cl = l & 15;
    int bh = b * 8 + h;
    int ic0 = ig * 8 + w * 2;

    // Q^T B-fragments for 2 row-chunks, loop-invariant
    bf16x8 qf[2][2];
#pragma unroll
    for (int rc = 0; rc < 2; rc++) {
        const unsigned short* qp = Qs + (size_t)(b * 2048 + ig * 128 + w * 32 + rc * 16 + cl) * 512 + h * 64 + q * 8;
        qf[rc][0] = *reinterpret_cast<const bf16x8*>(qp);
        qf[rc][1] = *reinterpret_cast<const bf16x8*>(qp + 32);
    }
    bf16x8 ones;
#pragma unroll
    for (int i = 0; i < 8; i++) { unsigned short o1 = 0x3F80; __builtin_memcpy(((unsigned short*)&ones) + i, &o1, 2); }

    f32x4 O[2][4];
    f32x4 Osum[2];
#pragma unroll
    for (int rc = 0; rc < 2; rc++) {
#pragma unroll
        for (int nt = 0; nt < 4; nt++)
#pragma unroll
            for (int r = 0; r < 4; r++) O[rc][nt][r] = 0.f;
#pragma unroll
        for (int r = 0; r < 4; r++) Osum[rc][r] = 0.f;
    }

    const unsigned short* Kh = Kb + (size_t)b * 2048 * 512 + h * 64;
    const unsigned short* Vh = Vt + ((size_t)bh * 64) * 2048;
    const unsigned short* mb0 = mq + (size_t)(b * 128 + ic0) * 32768 + l * 16 + (size_t)(js * 16) * 1024;
    const unsigned short* mb1 = mb0 + 32768;
    unsigned short* pw = &PA[w][0];
    int lrow = l >> 2, lch = (l & 3) * 8;
    int jb0 = js * 1024;

    // stage tile 0 into buf 0
#pragma unroll
    for (int e = 0; e < 2; e++) {
        int c = w * 2 + e, kk = c >> 2, r16 = (c & 3) * 16;
        GLDS16(Kh + (size_t)(jb0 + r16 + lrow) * 512 + kk * 32 + lch, &Ks[0][kk * 2048 + r16 * 32]);
        GLDS16(Vh + (size_t)(r16 + lrow) * 2048 + jb0 + kk * 32 + lch, &Vs[0][kk * 2048 + r16 * 32]);
    }
    // prefetch mc for tile 0
    u16x8 mcA[2][2], mcB[2][2];
    mcA[0][0] = *reinterpret_cast<const u16x8*>(mb0);
    mcA[0][1] = *reinterpret_cast<const u16x8*>(mb0 + 8);
    mcA[1][0] = *reinterpret_cast<const u16x8*>(mb1);
    mcA[1][1] = *reinterpret_cast<const u16x8*>(mb1 + 8);

// One tile body. BUF is a literal (static LDS addressing); MCC = mc regs for this tile
// (prefetched last iteration); MCN = regs to prefetch tile T+1 into; PRED = stage-next?
#define ATT_BODY(T, BUF, MCC, MCN, PRED) { \
    __syncthreads();   /* tile T staged (vmcnt drained pre-barrier; issued a full iter ago) */ \
    if (PRED) { \
        int jb = jb0 + ((T) + 1) * 64; \
        _Pragma("unroll") \
        for (int e = 0; e < 2; e++) { \
            int c = w * 2 + e, kk = c >> 2, r16 = (c & 3) * 16; \
            GLDS16(Kh + (size_t)(jb + r16 + lrow) * 512 + kk * 32 + lch, &Ks[(BUF) ^ 1][kk * 2048 + r16 * 32]); \
            GLDS16(Vh + (size_t)(r16 + lrow) * 2048 + jb + kk * 32 + lch, &Vs[(BUF) ^ 1][kk * 2048 + r16 * 32]); \
        } \
        size_t off = (size_t)((T) + 1) * 1024; \
        MCN[0][0] = *reinterpret_cast<const u16x8*>(mb0 + off); \
        MCN[0][1] = *reinterpret_cast<const u16x8*>(mb0 + off + 8); \
        MCN[1][0] = *reinterpret_cast<const u16x8*>(mb1 + off); \
        MCN[1][1] = *reinterpret_cast<const u16x8*>(mb1 + off + 8); \
    } \
    /* S^T = K.Q^T for both rc (K fragments read once) */ \
    f32x4 S[2][4]; \
    _Pragma("unroll") \
    for (int rc = 0; rc < 2; rc++) \
        _Pragma("unroll") \
        for (int mt = 0; mt < 4; mt++) \
            _Pragma("unroll") \
            for (int r = 0; r < 4; r++) S[rc][mt][r] = 0.f; \
    __builtin_amdgcn_s_setprio(1); \
    _Pragma("unroll") \
    for (int mt = 0; mt < 4; mt++) { \
        bf16x8 kf0 = *reinterpret_cast<const bf16x8*>(&Ks[BUF][(16 * mt + cl) * 32 + q * 8]); \
        bf16x8 kf1 = *reinterpret_cast<const bf16x8*>(&Ks[BUF][2048 + (16 * mt + cl) * 32 + q * 8]); \
        _Pragma("unroll") \
        for (int rc = 0; rc < 2; rc++) { \
            S[rc][mt] = __builtin_amdgcn_mfma_f32_16x16x32_bf16(kf0, qf[rc][0], S[rc][mt], 0, 0, 0); \
            S[rc][mt] = __builtin_amdgcn_mfma_f32_16x16x32_bf16(kf1, qf[rc][1], S[rc][mt], 0, 0, 0); \
        } \
    } \
    __builtin_amdgcn_s_setprio(0); \
    /* per rc: p = exp2(S^T)*m -> PA (b64 writes) */ \
    _Pragma("unroll") \
    for (int rc = 0; rc < 2; rc++) { \
        _Pragma("unroll") \
        for (int mt = 0; mt < 4; mt++) { \
            float p0 = fexp2(S[rc][mt][0]) * bu2f((mt < 2) ? MCC[rc][0][mt * 4 + 0] : MCC[rc][1][(mt - 2) * 4 + 0]); \
            float p1 = fexp2(S[rc][mt][1]) * bu2f((mt < 2) ? MCC[rc][0][mt * 4 + 1] : MCC[rc][1][(mt - 2) * 4 + 1]); \
            float p2 = fexp2(S[rc][mt][2]) * bu2f((mt < 2) ? MCC[rc][0][mt * 4 + 2] : MCC[rc][1][(mt - 2) * 4 + 2]); \
            float p3 = fexp2(S[rc][mt][3]) * bu2f((mt < 2) ? MCC[rc][0][mt * 4 + 3] : MCC[rc][1][(mt - 2) * 4 + 3]); \
            ushort4 o; \
            o.x = f2bu(p0); o.y = f2bu(p1); o.z = f2bu(p2); o.w = f2bu(p3); \
            *reinterpret_cast<ushort4*>(pw + rc * (16 * 72) + cl * 72 + 16 * mt + q * 4) = o; \
        } \
    } \
    /* O += P.V: per jc read both rc P-fragments, stream V fragments once */ \
    __builtin_amdgcn_s_setprio(1); \
    _Pragma("unroll") \
    for (int jc = 0; jc < 2; jc++) { \
        bf16x8 pf0 = *reinterpret_cast<const bf16x8*>(pw + cl * 72 + jc * 32 + q * 8); \
        bf16x8 pf1 = *reinterpret_cast<const bf16x8*>(pw + 16 * 72 + cl * 72 + jc * 32 + q * 8); \
        _Pragma("unroll") \
        for (int nt = 0; nt < 4; nt++) { \
            bf16x8 vf = *reinterpret_cast<const bf16x8*>(&Vs[BUF][jc * 2048 + (16 * nt + cl) * 32 + q * 8]); \
            O[0][nt] = __builtin_amdgcn_mfma_f32_16x16x32_bf16(pf0, vf, O[0][nt], 0, 0, 0); \
            O[1][nt] = __builtin_amdgcn_mfma_f32_16x16x32_bf16(pf1, vf, O[1][nt], 0, 0, 0); \
        } \
        Osum[0] = __builtin_amdgcn_mfma_f32_16x16x32_bf16(pf0, ones, Osum[0], 0, 0, 0); \
        Osum[1] = __builtin_amdgcn_mfma_f32_16x16x32_bf16(pf1, ones, Osum[1], 0, 0, 0); \
    } \
    __builtin_amdgcn_s_setprio(0); \
}

    for (int tt = 0; tt < 8; tt++) {
        int t0 = tt * 2;
        ATT_BODY(t0, 0, mcA, mcB, 1)
        ATT_BODY(t0 + 1, 1, mcB, mcA, (tt < 7))
    }
#undef ATT_BODY

    // epilogue: write bf16 partial O (lane-packed, 16B stores) + row sums
    typedef unsigned short u16x8s __attribute__((ext_vector_type(8)));
#pragma unroll
    for (int rc = 0; rc < 2; rc++) {
        size_t chunk = ((size_t)(bh * 128 + ic0 + rc)) * 2 + js;
        unsigned short* po = PO + chunk * 1024 + l * 16;
        u16x8s o01, o23;
#pragma unroll
        for (int nt = 0; nt < 4; nt++) {
            o01[nt]     = f2bu(O[rc][nt][0]);
            o01[4 + nt] = f2bu(O[rc][nt][1]);
            o23[nt]     = f2bu(O[rc][nt][2]);
            o23[4 + nt] = f2bu(O[rc][nt][3]);
        }
        *reinterpret_cast<u16x8s*>(po) = o01;
        *reinterpret_cast<u16x8s*>(po + 8) = o23;
        if (cl == 0) {
#pragma unroll
            for (int r = 0; r < 4; r++)
                PL[chunk * 16 + q * 4 + r] = Osum[rc][r];
        }
    }
}

// ---------------- combine 2 j-halves, normalize, residual ----------------
// 512 blocks (bh*32 + t64) x 256 thr; each block 4 row-chunks (64 rows).
__global__ void k_comb(const unsigned short* __restrict__ PO, const float* __restrict__ PL,
                       const float* __restrict__ x, float* __restrict__ out) {
    int blk = blockIdx.x;
    int t64 = blk & 31, bh = blk >> 5;
    int b = bh >> 3, h = bh & 7;
    int t = threadIdx.x;               // t = l*4 + r
    int l = t >> 2, r = t & 3, q = l >> 4, cl = l & 15;
#pragma unroll
    for (int w = 0; w < 4; w++) {
        int ic = t64 * 4 + w;
        size_t c0 = ((size_t)(bh * 128 + ic)) * 2;
        float o0 = 0.f, o1 = 0.f, o2 = 0.f, o3 = 0.f, lsum = 0.f;
#pragma unroll
        for (int js = 0; js < 2; js++) {
            ushort4 a = *reinterpret_cast<const ushort4*>(PO + (c0 + js) * 1024 + t * 4);
            o0 += bu2f(a.x); o1 += bu2f(a.y); o2 += bu2f(a.z); o3 += bu2f(a.w);
            lsum += PL[(c0 + js) * 16 + q * 4 + r];
        }
        float inv = 1.0f / lsum;
        size_t gro = (size_t)(b * 2048 + ic * 16 + q * 4 + r) * 512 + h * 64;
        out[gro + 0 * 16 + cl] = o0 * inv + x[gro + 0 * 16 + cl];
        out[gro + 1 * 16 + cl] = o1 * inv + x[gro + 1 * 16 + cl];
        out[gro + 2 * 16 + cl] = o2 * inv + x[gro + 2 * 16 + cl];
        out[gro + 3 * 16 + cl] = o3 * inv + x[gro + 3 * 16 + cl];
    }
}

extern "C" void kernel_launch(void* const* d_in, const int* in_sizes, int n_in,
                              void* d_out, int out_size, void* d_ws, size_t ws_size,
                              hipStream_t stream) {
    const float* x   = (const float*)d_in[0];
    const float* adj = (const float*)d_in[1];
    const float* Wq  = (const float*)d_in[2];
    const float* bq  = (const float*)d_in[3];
    const float* Wk  = (const float*)d_in[4];
    const float* bk  = (const float*)d_in[5];
    const float* Wv  = (const float*)d_in[6];
    const float* bv  = (const float*)d_in[7];
    const float* wg  = (const float*)d_in[8];
    // d_in[9] (b_g) unused: row-constant bias cancels in softmax
    float* out = (float*)d_out;
    char* ws = (char*)d_ws;
    unsigned short* Qs = (unsigned short*)(ws + OFF_QS);
    unsigned short* Kb = (unsigned short*)(ws + OFF_KB);
    unsigned short* Vt = (unsigned short*)(ws + OFF_VT);
    float* cv2 = (float*)(ws + OFF_CV);
    unsigned short* xb = (unsigned short*)(ws + OFF_XB);
    unsigned short* wt = (unsigned short*)(ws + OFF_WT);
    unsigned short* mqp = (unsigned short*)(ws + OFF_MQ);
    unsigned short* PO = (unsigned short*)(ws + OFF_PO);
    float* PL = (float*)(ws + OFF_PL);

    k_prepwt<<<1216, 256, 0, stream>>>(x, wg, Wq, Wk, Wv, xb, cv2, wt);
    k_mid<<<4480, 256, 0, stream>>>(adj, cv2, mqp, xb, wt, bq, bk, bv, Qs, Kb, Vt);
    k_attn<<<512, 256, 0, stream>>>(Qs, Kb, Vt, mqp, PO, PL);
    k_comb<<<512, 256, 0, stream>>>(PO, PL, x, out);
}